// Round 5
// baseline (331.996 us; speedup 1.0000x reference)
//
#include <hip/hip_runtime.h>
#include <hip/hip_bf16.h>

typedef unsigned short u16;
typedef __bf16 bf16x8 __attribute__((ext_vector_type(8)));
typedef float  f32x4  __attribute__((ext_vector_type(4)));
typedef u16    u16x8  __attribute__((ext_vector_type(8)));

__device__ __forceinline__ u16 f2bf(float f) {
    unsigned u = __float_as_uint(f);
    u = (u + 0x7fffu + ((u >> 16) & 1u)) >> 16;   // RNE
    return (u16)u;
}
__device__ __forceinline__ float bf2f(u16 h) {
    return __uint_as_float(((unsigned)h) << 16);
}

// ---------------------------------------------------------------- convert (3 tensors per dispatch)
__global__ __launch_bounds__(256) void cvt3_bf16_kernel(
    const float* __restrict__ s0, const float* __restrict__ s1,
    const float* __restrict__ s2, u16* __restrict__ dst, size_t dstride, int n8)
{
    int i = blockIdx.x * 256 + threadIdx.x;
    if (i >= n8) return;
    const float* src = (blockIdx.z == 0) ? s0 : (blockIdx.z == 1) ? s1 : s2;
    u16* d = dst + (size_t)blockIdx.z * dstride;
    const float4* s4 = (const float4*)src;
    float4 a = s4[2 * i], b = s4[2 * i + 1];
    u16x8 o;
    o[0] = f2bf(a.x); o[1] = f2bf(a.y); o[2] = f2bf(a.z); o[3] = f2bf(a.w);
    o[4] = f2bf(b.x); o[5] = f2bf(b.y); o[6] = f2bf(b.z); o[7] = f2bf(b.w);
    ((u16x8*)d)[i] = o;
}

// ---------------------------------------------------------------- GEMM C = A*B^T
// BM=256, BN=128, BK=32, 8 waves (4M x 2N), wave tile 64x64.
// 3 LDS buffers x 24KB = 72KB -> 2 blocks/CU (cross-block TLP covers drains).
// One phase/tile: stage(t+2) -> read 8 frags -> 16 MFMA -> vmcnt(3) -> barrier.
// T1 XCD remap + L2 shaping; T2 swizzle (2-way max); T5 setprio.
#define BUF_U 12288            // u16 per buffer: A 256*32=8192 + B 128*32=4096
#define LDS_B (3 * BUF_U * 2)  // 73728 bytes

__device__ __forceinline__ void gload_lds16(const void* g, void* l) {
    __builtin_amdgcn_global_load_lds(
        (__attribute__((address_space(1))) void*)g,
        (__attribute__((address_space(3))) void*)l, 16, 0, 0);
}

__device__ __forceinline__ int swz_g(int r) {   // involution row hash, 2-way banks
    return (r & 3) ^ (((r >> 2) & 1) << 1) ^ ((r >> 3) & 1);
}

template<bool OUT_BF16, bool HAS_BIAS>
__global__ __launch_bounds__(512, 4) void gemm_k32(
    const u16* __restrict__ A, const u16* __restrict__ Bm,
    const float* __restrict__ bias, void* __restrict__ C,
    int M, int N, int K, float scale,
    long long aBS, long long bBS, long long cBS)
{
    extern __shared__ u16 lds[];

    // ---- T1: XCD-aware remap + L2 group shaping (4 m-rows per group) ----
    const int gx = gridDim.x, gy = gridDim.y;
    const int slab = gx * gy;
    const int nwg  = slab * gridDim.z;
    const int b    = blockIdx.x + gx * (blockIdx.y + gy * blockIdx.z);
    const int qc   = nwg >> 3;
    const int L    = (b & 7) * qc + (b >> 3);
    const int tz   = L / slab;
    const int rr   = L - tz * slab;
    const int g4   = rr / (gx * 4);
    const int w4   = rr - g4 * (gx * 4);
    const int tx   = w4 >> 2;
    const int ty   = g4 * 4 + (w4 & 3);

    A  += (size_t)tz * aBS;
    Bm += (size_t)tz * bBS;

    const int m0 = ty * 256;
    const int n0 = tx * 128;
    const int tid  = threadIdx.x;
    const int lane = tid & 63;
    const int wave = tid >> 6;          // 0..7
    const int wm   = wave >> 1;         // 0..3
    const int wn   = wave & 1;          // 0..1
    const int fr   = lane & 15;
    const int kg   = lane >> 4;         // 0..3

    // ---- staging: linear LDS dest (wave base), inverse-swizzled global src
    const int r_ = tid >> 2;                         // 0..127
    const int s_ = (tid & 3) ^ swz_g(r_);            // swizzled 16B slot
    const u16* gA = A  + (size_t)(m0 + r_) * K + s_ * 8;
    const u16* gB = Bm + (size_t)(n0 + r_) * K + s_ * 8;
    const int dstW = wave * 512;                     // u16; + lane*8 implicit

    auto stA = [&](u16* bufb, int tk, int c) {       // c = 0..1 (128 rows each)
        gload_lds16(gA + (size_t)c * 128 * K + tk * 32, bufb + c * 4096 + dstW);
    };
    auto stB = [&](u16* bufb, int tk) {
        gload_lds16(gB + tk * 32, bufb + 8192 + dstW);
    };

    // ---- fragment reads (swizzled slot)
    auto rdA = [&](const u16* sa, int m) {
        const int R  = wm * 64 + m * 16 + fr;
        const int sl = kg ^ swz_g(R);
        return *(const bf16x8*)&sa[R * 32 + sl * 8];
    };
    auto rdB = [&](const u16* sb, int n) {
        const int R  = wn * 64 + n * 16 + fr;
        const int sl = kg ^ swz_g(R);
        return *(const bf16x8*)&sb[R * 32 + sl * 8];
    };

    f32x4 acc[4][4] = {};
    const int NT = K / 32;

    u16 *p0 = lds, *p1 = lds + BUF_U, *p2 = lds + 2 * BUF_U;

    // ---- prologue: stage t0->p0, t1->p1; ensure t0 resident (t1 in flight)
    stA(p0, 0, 0); stA(p0, 0, 1); stB(p0, 0);
    stA(p1, 1, 0); stA(p1, 1, 1); stB(p1, 1);
    asm volatile("s_waitcnt vmcnt(3)" ::: "memory");
    __builtin_amdgcn_s_barrier();

    for (int t = 0; t < NT; ++t) {
        const bool st = (t + 2 < NT);
        if (st) { stA(p2, t + 2, 0); stA(p2, t + 2, 1); stB(p2, t + 2); }

        bf16x8 a[4], bfr[4];
        #pragma unroll
        for (int m = 0; m < 4; ++m) a[m] = rdA(p0, m);
        #pragma unroll
        for (int n = 0; n < 4; ++n) bfr[n] = rdB(p0 + 8192, n);

        __builtin_amdgcn_s_setprio(1);
        #pragma unroll
        for (int m = 0; m < 4; ++m)
            #pragma unroll
            for (int n = 0; n < 4; ++n)
                acc[m][n] = __builtin_amdgcn_mfma_f32_16x16x32_bf16(
                    a[m], bfr[n], acc[m][n], 0, 0, 0);
        __builtin_amdgcn_s_setprio(0);

        if (t + 1 < NT) {
            if (st) asm volatile("s_waitcnt vmcnt(3)" ::: "memory");
            else    asm volatile("s_waitcnt vmcnt(0)" ::: "memory");
            __builtin_amdgcn_s_barrier();
        }
        u16* tmp = p0; p0 = p1; p1 = p2; p2 = tmp;
    }

    // ---- epilogue: row = m0+wm*64+m*16+kg*4+q, col = n0+wn*64+n*16+fr
    if (OUT_BF16) {
        u16* Cb = (u16*)C + (size_t)tz * cBS;
        #pragma unroll
        for (int m = 0; m < 4; ++m) {
            const int row0 = m0 + wm * 64 + m * 16 + kg * 4;
            #pragma unroll
            for (int n = 0; n < 4; ++n) {
                const int col = n0 + wn * 64 + n * 16 + fr;
                const float badd = HAS_BIAS ? bias[col] : 0.0f;
                f32x4 v = acc[m][n];
                #pragma unroll
                for (int q = 0; q < 4; ++q)
                    Cb[(size_t)(row0 + q) * N + col] = f2bf(v[q] * scale + badd);
            }
        }
    } else {
        float* Cf = (float*)C + (size_t)tz * cBS;
        #pragma unroll
        for (int m = 0; m < 4; ++m) {
            const int row0 = m0 + wm * 64 + m * 16 + kg * 4;
            #pragma unroll
            for (int n = 0; n < 4; ++n) {
                const int col = n0 + wn * 64 + n * 16 + fr;
                const float badd = HAS_BIAS ? bias[col] : 0.0f;
                f32x4 v = acc[m][n];
                #pragma unroll
                for (int q = 0; q < 4; ++q)
                    Cf[(size_t)(row0 + q) * N + col] = v[q] * scale + badd;
            }
        }
    }
}

// ---------------------------------------------------------------- V transpose
__global__ __launch_bounds__(256) void transpose_bf16(
    const u16* __restrict__ V, u16* __restrict__ Vt)
{
    __shared__ u16 tile[64][72];
    const int b  = blockIdx.z;
    const int k0 = blockIdx.y * 64;
    const int d0 = blockIdx.x * 64;
    const int tr = threadIdx.x >> 3;
    const int tc = (threadIdx.x & 7) * 8;

    const u16* src = V + ((size_t)b * 2048 + k0) * 1024 + d0;
    #pragma unroll
    for (int i = 0; i < 2; ++i) {
        int r = tr + i * 32;
        *(u16x8*)&tile[r][tc] = *(const u16x8*)&src[(size_t)r * 1024 + tc];
    }
    __syncthreads();
    u16* dst = Vt + ((size_t)b * 1024 + d0) * 2048 + k0;
    #pragma unroll
    for (int i = 0; i < 2; ++i) {
        int r = tr + i * 32;
        u16x8 o;
        #pragma unroll
        for (int j = 0; j < 8; ++j) o[j] = tile[tc + j][r];
        *(u16x8*)&dst[(size_t)r * 2048 + tc] = o;
    }
}

// ---------------------------------------------------------------- softmax (in-place, bf16)
__global__ __launch_bounds__(256) void softmax_kernel(u16* __restrict__ SP)
{
    const size_t row = blockIdx.x;
    u16x8* rp = (u16x8*)(SP + row * 2048);
    const int tid  = threadIdx.x;
    const int lane = tid & 63;
    const int wv   = tid >> 6;

    u16x8 v = rp[tid];
    float f[8];
    #pragma unroll
    for (int j = 0; j < 8; ++j) f[j] = bf2f(v[j]);

    float m = f[0];
    #pragma unroll
    for (int j = 1; j < 8; ++j) m = fmaxf(m, f[j]);
    #pragma unroll
    for (int o = 32; o; o >>= 1) m = fmaxf(m, __shfl_xor(m, o, 64));

    __shared__ float red[8];
    if (lane == 0) red[wv] = m;
    __syncthreads();
    m = fmaxf(fmaxf(red[0], red[1]), fmaxf(red[2], red[3]));

    float e[8], s = 0.f;
    #pragma unroll
    for (int j = 0; j < 8; ++j) { e[j] = __expf(f[j] - m); s += e[j]; }
    #pragma unroll
    for (int o = 32; o; o >>= 1) s += __shfl_xor(s, o, 64);
    if (lane == 0) red[4 + wv] = s;
    __syncthreads();
    s = (red[4] + red[5]) + (red[6] + red[7]);
    const float inv = 1.0f / s;

    u16x8 o8;
    #pragma unroll
    for (int j = 0; j < 8; ++j) o8[j] = f2bf(e[j] * inv);
    rp[tid] = o8;
}

// ---------------------------------------------------------------- launch
extern "C" void kernel_launch(void* const* d_in, const int* in_sizes, int n_in,
                              void* d_out, int out_size, void* d_ws, size_t ws_size,
                              hipStream_t stream)
{
    const int Bn = 4, S = 2048, D = 1024;
    const size_t nx = (size_t)Bn * S * D;
    const size_t nw = (size_t)D * D;

    const float* x  = (const float*)d_in[0];
    const float* y  = (const float*)d_in[1];
    const float* z  = (const float*)d_in[2];
    const float* Wq = (const float*)d_in[3];
    const float* bq = (const float*)d_in[4];
    const float* Wk = (const float*)d_in[5];
    const float* bk = (const float*)d_in[6];
    const float* Wv = (const float*)d_in[7];
    const float* bv = (const float*)d_in[8];

    u16* xb  = (u16*)d_ws;
    u16* yb  = xb + nx;
    u16* zb  = yb + nx;
    u16* wqb = zb + nx;
    u16* wkb = wqb + nw;
    u16* wvb = wkb + nw;
    u16* Qb  = wvb + nw;
    u16* Kb  = Qb + nx;
    u16* Vb  = Kb + nx;
    u16* Vt  = Vb + nx;
    u16* Pb  = xb;          // P [B][S][S] aliases xb+yb (dead after Q/K GEMMs)

    hipFuncSetAttribute((const void*)gemm_k32<true,  true >,
                        hipFuncAttributeMaxDynamicSharedMemorySize, LDS_B);
    hipFuncSetAttribute((const void*)gemm_k32<true,  false>,
                        hipFuncAttributeMaxDynamicSharedMemorySize, LDS_B);
    hipFuncSetAttribute((const void*)gemm_k32<false, false>,
                        hipFuncAttributeMaxDynamicSharedMemorySize, LDS_B);

    const int n8x = (int)(nx / 8), n8w = (int)(nw / 8);
    cvt3_bf16_kernel<<<dim3((n8x + 255) / 256, 1, 3), 256, 0, stream>>>(
        x, y, z, xb, nx, n8x);
    cvt3_bf16_kernel<<<dim3((n8w + 255) / 256, 1, 3), 256, 0, stream>>>(
        Wq, Wk, Wv, wqb, nw, n8w);

    dim3 gQKV(D / 128, (Bn * S) / 256, 1);       // 8 x 32 = 256 blocks
    gemm_k32<true, true><<<gQKV, 512, LDS_B, stream>>>(xb, wqb, bq, Qb, Bn * S, D, D, 1.0f, 0, 0, 0);
    gemm_k32<true, true><<<gQKV, 512, LDS_B, stream>>>(yb, wkb, bk, Kb, Bn * S, D, D, 1.0f, 0, 0, 0);
    gemm_k32<true, true><<<gQKV, 512, LDS_B, stream>>>(zb, wvb, bv, Vb, Bn * S, D, D, 1.0f, 0, 0, 0);

    transpose_bf16<<<dim3(D / 64, S / 64, Bn), 256, 0, stream>>>(Vb, Vt);

    // scores: P = (Q K^T) / 32   (16 x 8 x 4 = 512 blocks)
    gemm_k32<true, false><<<dim3(S / 128, S / 256, Bn), 512, LDS_B, stream>>>(
        Qb, Kb, nullptr, Pb, S, S, D, 0.03125f,
        (long long)S * D, (long long)S * D, (long long)S * S);

    softmax_kernel<<<Bn * S, 256, 0, stream>>>(Pb);

    // out = P @ V (via Vt), fp32   (8 x 8 x 4 = 256 blocks)
    gemm_k32<false, false><<<dim3(D / 128, S / 256, Bn), 512, LDS_B, stream>>>(
        Pb, Vt, nullptr, d_out, S, D, S, 1.0f,
        (long long)S * S, (long long)D * S, (long long)S * D);
}

// Round 7
// 323.217 us; speedup vs baseline: 1.0272x; 1.0272x over previous
//
#include <hip/hip_runtime.h>
#include <hip/hip_bf16.h>

typedef unsigned short u16;
typedef __bf16 bf16x8 __attribute__((ext_vector_type(8)));
typedef float  f32x4  __attribute__((ext_vector_type(4)));
typedef u16    u16x8  __attribute__((ext_vector_type(8)));

__device__ __forceinline__ u16 f2bf(float f) {
    unsigned u = __float_as_uint(f);
    u = (u + 0x7fffu + ((u >> 16) & 1u)) >> 16;   // RNE
    return (u16)u;
}
__device__ __forceinline__ float bf2f(u16 h) {
    return __uint_as_float(((unsigned)h) << 16);
}

// ---------------------------------------------------------------- convert (3 tensors per dispatch)
__global__ __launch_bounds__(256) void cvt3_bf16_kernel(
    const float* __restrict__ s0, const float* __restrict__ s1,
    const float* __restrict__ s2, u16* __restrict__ dst, size_t dstride, int n8)
{
    int i = blockIdx.x * 256 + threadIdx.x;
    if (i >= n8) return;
    const float* src = (blockIdx.z == 0) ? s0 : (blockIdx.z == 1) ? s1 : s2;
    u16* d = dst + (size_t)blockIdx.z * dstride;
    const float4* s4 = (const float4*)src;
    float4 a = s4[2 * i], b = s4[2 * i + 1];
    u16x8 o;
    o[0] = f2bf(a.x); o[1] = f2bf(a.y); o[2] = f2bf(a.z); o[3] = f2bf(a.w);
    o[4] = f2bf(b.x); o[5] = f2bf(b.y); o[6] = f2bf(b.z); o[7] = f2bf(b.w);
    ((u16x8*)d)[i] = o;
}

// ---------------------------------------------------------------- GEMM C = A*B^T
// m201-cell port: BM=256, BN in {256,128}, BK=64, 8 waves (2M x 4N).
// 4 quadrant-phases per K-tile, B-frags held in regs across the K-tile,
// asm s_barrier per phase (cross-wave read<->MFMA skew), setprio on MFMA,
// 2 static LDS buffers distance-2, burst staging after read-retire barrier,
// counted vmcnt(G) (never 0 mid-loop), R3-proven XOR swizzle.
__device__ __forceinline__ void gload_lds16(const void* g, void* l) {
    __builtin_amdgcn_global_load_lds(
        (__attribute__((address_space(1))) void*)g,
        (__attribute__((address_space(3))) void*)l, 16, 0, 0);
}

template<int BN_, bool OUT_BF16, bool HAS_BIAS>
__global__ __launch_bounds__(512, 2) void gemm_c8(
    const u16* __restrict__ A, const u16* __restrict__ Bm,
    const float* __restrict__ bias, void* __restrict__ C,
    int M, int N, int K, float scale,
    long long aBS, long long bBS, long long cBS)
{
    constexpr int NF   = BN_ / 64;          // n-frags per wave (4 or 2)
    constexpr int NB   = (BN_ * 64 * 2) / 8192;  // B stage calls (4 or 2)
    constexpr int BUFU = 16384 + BN_ * 64;  // u16 per buffer
    constexpr int WN   = BN_ / 4;           // wave n-span
    extern __shared__ u16 lds[];

    // ---- T1: XCD-aware remap + L2 group shaping (4 m-rows per group) ----
    const int gx = gridDim.x, gy = gridDim.y;
    const int slab = gx * gy;
    const int nwg  = slab * gridDim.z;
    const int b    = blockIdx.x + gx * (blockIdx.y + gy * blockIdx.z);
    const int qc   = nwg >> 3;
    const int L    = (b & 7) * qc + (b >> 3);
    const int tz   = L / slab;
    const int rr   = L - tz * slab;
    const int g4   = rr / (gx * 4);
    const int w4   = rr - g4 * (gx * 4);
    const int tx   = w4 >> 2;
    const int ty   = g4 * 4 + (w4 & 3);

    A  += (size_t)tz * aBS;
    Bm += (size_t)tz * bBS;

    const int m0 = ty * 256;
    const int n0 = tx * BN_;
    const int tid  = threadIdx.x;
    const int lane = tid & 63;
    const int wave = tid >> 6;          // 0..7
    const int wm   = wave >> 2;         // 0..1
    const int wn   = wave & 3;          // 0..3
    const int fr   = lane & 15;
    const int kg   = lane >> 4;         // 0..3

    // ---- staging: linear LDS dest, inverse-swizzled global source
    const int r_  = tid >> 3;                    // 0..63 row within 64-row chunk
    const int sw8 = ((tid & 7) ^ (r_ & 7)) * 8;  // swizzled 16B slot (u16 units)
    const u16* gA = A  + (size_t)(m0 + r_) * K + sw8;
    const u16* gB = Bm + (size_t)(n0 + r_) * K + sw8;
    const int dstW = wave * 512;                 // u16

    auto stage = [&](int db, int t) {
        u16* dst = lds + db * BUFU;
        #pragma unroll
        for (int c = 0; c < 4; ++c)
            gload_lds16(gA + (size_t)c * 64 * K + t * 64, dst + c * 4096 + dstW);
        #pragma unroll
        for (int c = 0; c < NB; ++c)
            gload_lds16(gB + (size_t)c * 64 * K + t * 64, dst + 16384 + c * 4096 + dstW);
    };

    // ---- fragment read: row R, k-chunk ck in [0,8); slot = ck ^ (R&7)
    auto rdT = [&](const u16* base, int R, int ck) {
        return *(const bf16x8*)&base[R * 64 + ((ck ^ (R & 7)) << 3)];
    };

    f32x4 acc[8][NF] = {};
    bf16x8 bF[NF][2];
    const int NT = K / 64;

    // ---- prologue: stage t0->buf0, t1->buf1; wait t0 (t1's G in flight)
    stage(0, 0);
    stage(1, 1);
    if constexpr (NB == 4) asm volatile("s_waitcnt vmcnt(8)" ::: "memory");
    else                   asm volatile("s_waitcnt vmcnt(6)" ::: "memory");
    asm volatile("s_barrier" ::: "memory");

    for (int i = 0; i < NT / 2; ++i) {
        const int t = 2 * i;
        #pragma unroll
        for (int half = 0; half < 2; ++half) {
            const u16* sa = lds + half * BUFU;
            const u16* sb = sa + 16384;

            #pragma unroll
            for (int q = 0; q < 4; ++q) {
                if (q == 0) {
                    #pragma unroll
                    for (int nf = 0; nf < NF; ++nf)
                        #pragma unroll
                        for (int ks = 0; ks < 2; ++ks)
                            bF[nf][ks] = rdT(sb, wn * WN + nf * 16 + fr, ks * 4 + kg);
                }
                bf16x8 aF[2][2];
                #pragma unroll
                for (int mi = 0; mi < 2; ++mi)
                    #pragma unroll
                    for (int ks = 0; ks < 2; ++ks)
                        aF[mi][ks] = rdT(sa, wm * 128 + q * 32 + mi * 16 + fr, ks * 4 + kg);

                __builtin_amdgcn_s_setprio(1);
                #pragma unroll
                for (int mi = 0; mi < 2; ++mi)
                    #pragma unroll
                    for (int nf = 0; nf < NF; ++nf)
                        #pragma unroll
                        for (int ks = 0; ks < 2; ++ks)
                            acc[q * 2 + mi][nf] = __builtin_amdgcn_mfma_f32_16x16x32_bf16(
                                aF[mi][ks], bF[nf][ks], acc[q * 2 + mi][nf], 0, 0, 0);
                __builtin_amdgcn_s_setprio(0);
                asm volatile("s_barrier" ::: "memory");
            }

            // tile-boundary: restage the buffer just retired, counted wait
            const int tn = t + half + 2;
            if (tn < NT) {
                stage(half, tn);
                if constexpr (NB == 4) asm volatile("s_waitcnt vmcnt(8)" ::: "memory");
                else                   asm volatile("s_waitcnt vmcnt(6)" ::: "memory");
            } else {
                asm volatile("s_waitcnt vmcnt(0)" ::: "memory");
            }
            asm volatile("s_barrier" ::: "memory");
        }
    }

    // ---- epilogue: row = m0+wm*128+mf*16+kg*4+q, col = n0+wn*WN+nf*16+fr
    if (OUT_BF16) {
        u16* Cb = (u16*)C + (size_t)tz * cBS;
        #pragma unroll
        for (int mf = 0; mf < 8; ++mf) {
            const int row0 = m0 + wm * 128 + mf * 16 + kg * 4;
            #pragma unroll
            for (int nf = 0; nf < NF; ++nf) {
                const int col = n0 + wn * WN + nf * 16 + fr;
                const float badd = HAS_BIAS ? bias[col] : 0.0f;
                f32x4 v = acc[mf][nf];
                #pragma unroll
                for (int q = 0; q < 4; ++q)
                    Cb[(size_t)(row0 + q) * N + col] = f2bf(v[q] * scale + badd);
            }
        }
    } else {
        float* Cf = (float*)C + (size_t)tz * cBS;
        #pragma unroll
        for (int mf = 0; mf < 8; ++mf) {
            const int row0 = m0 + wm * 128 + mf * 16 + kg * 4;
            #pragma unroll
            for (int nf = 0; nf < NF; ++nf) {
                const int col = n0 + wn * WN + nf * 16 + fr;
                const float badd = HAS_BIAS ? bias[col] : 0.0f;
                f32x4 v = acc[mf][nf];
                #pragma unroll
                for (int q = 0; q < 4; ++q)
                    Cf[(size_t)(row0 + q) * N + col] = v[q] * scale + badd;
            }
        }
    }
}

// ---------------------------------------------------------------- V transpose
__global__ __launch_bounds__(256) void transpose_bf16(
    const u16* __restrict__ V, u16* __restrict__ Vt)
{
    __shared__ u16 tile[64][72];
    const int b  = blockIdx.z;
    const int k0 = blockIdx.y * 64;
    const int d0 = blockIdx.x * 64;
    const int tr = threadIdx.x >> 3;
    const int tc = (threadIdx.x & 7) * 8;

    const u16* src = V + ((size_t)b * 2048 + k0) * 1024 + d0;
    #pragma unroll
    for (int i = 0; i < 2; ++i) {
        int r = tr + i * 32;
        *(u16x8*)&tile[r][tc] = *(const u16x8*)&src[(size_t)r * 1024 + tc];
    }
    __syncthreads();
    u16* dst = Vt + ((size_t)b * 1024 + d0) * 2048 + k0;
    #pragma unroll
    for (int i = 0; i < 2; ++i) {
        int r = tr + i * 32;
        u16x8 o;
        #pragma unroll
        for (int j = 0; j < 8; ++j) o[j] = tile[tc + j][r];
        *(u16x8*)&dst[(size_t)r * 2048 + tc] = o;
    }
}

// ---------------------------------------------------------------- softmax (in-place, bf16)
__global__ __launch_bounds__(256) void softmax_kernel(u16* __restrict__ SP)
{
    const size_t row = blockIdx.x;
    u16x8* rp = (u16x8*)(SP + row * 2048);
    const int tid  = threadIdx.x;
    const int lane = tid & 63;
    const int wv   = tid >> 6;

    u16x8 v = rp[tid];
    float f[8];
    #pragma unroll
    for (int j = 0; j < 8; ++j) f[j] = bf2f(v[j]);

    float m = f[0];
    #pragma unroll
    for (int j = 1; j < 8; ++j) m = fmaxf(m, f[j]);
    #pragma unroll
    for (int o = 32; o; o >>= 1) m = fmaxf(m, __shfl_xor(m, o, 64));

    __shared__ float red[8];
    if (lane == 0) red[wv] = m;
    __syncthreads();
    m = fmaxf(fmaxf(red[0], red[1]), fmaxf(red[2], red[3]));

    float e[8], s = 0.f;
    #pragma unroll
    for (int j = 0; j < 8; ++j) { e[j] = __expf(f[j] - m); s += e[j]; }
    #pragma unroll
    for (int o = 32; o; o >>= 1) s += __shfl_xor(s, o, 64);
    if (lane == 0) red[4 + wv] = s;
    __syncthreads();
    s = (red[4] + red[5]) + (red[6] + red[7]);
    const float inv = 1.0f / s;

    u16x8 o8;
    #pragma unroll
    for (int j = 0; j < 8; ++j) o8[j] = f2bf(e[j] * inv);
    rp[tid] = o8;
}

// ---------------------------------------------------------------- launch
extern "C" void kernel_launch(void* const* d_in, const int* in_sizes, int n_in,
                              void* d_out, int out_size, void* d_ws, size_t ws_size,
                              hipStream_t stream)
{
    const int Bn = 4, S = 2048, D = 1024;
    const size_t nx = (size_t)Bn * S * D;
    const size_t nw = (size_t)D * D;

    const float* x  = (const float*)d_in[0];
    const float* y  = (const float*)d_in[1];
    const float* z  = (const float*)d_in[2];
    const float* Wq = (const float*)d_in[3];
    const float* bq = (const float*)d_in[4];
    const float* Wk = (const float*)d_in[5];
    const float* bk = (const float*)d_in[6];
    const float* Wv = (const float*)d_in[7];
    const float* bv = (const float*)d_in[8];

    u16* xb  = (u16*)d_ws;
    u16* yb  = xb + nx;
    u16* zb  = yb + nx;
    u16* wqb = zb + nx;
    u16* wkb = wqb + nw;
    u16* wvb = wkb + nw;
    u16* Qb  = wvb + nw;
    u16* Kb  = Qb + nx;
    u16* Vb  = Kb + nx;
    u16* Vt  = Vb + nx;
    u16* Pb  = xb;          // P [B][S][S] aliases xb+yb (dead after Q/K GEMMs)

    const int LDS_QKV = (16384 + 128 * 64) * 2 * 2;   // 96 KiB (BN=128)
    const int LDS_SC  = (16384 + 256 * 64) * 2 * 2;   // 128 KiB (BN=256)

    hipFuncSetAttribute((const void*)gemm_c8<128, true,  true >,
                        hipFuncAttributeMaxDynamicSharedMemorySize, LDS_QKV);
    hipFuncSetAttribute((const void*)gemm_c8<256, true,  false>,
                        hipFuncAttributeMaxDynamicSharedMemorySize, LDS_SC);
    hipFuncSetAttribute((const void*)gemm_c8<128, false, false>,
                        hipFuncAttributeMaxDynamicSharedMemorySize, LDS_QKV);

    const int n8x = (int)(nx / 8), n8w = (int)(nw / 8);
    cvt3_bf16_kernel<<<dim3((n8x + 255) / 256, 1, 3), 256, 0, stream>>>(
        x, y, z, xb, nx, n8x);
    cvt3_bf16_kernel<<<dim3((n8w + 255) / 256, 1, 3), 256, 0, stream>>>(
        Wq, Wk, Wv, wqb, nw, n8w);

    dim3 gQKV(D / 128, (Bn * S) / 256, 1);       // 8 x 32 = 256 blocks
    gemm_c8<128, true, true><<<gQKV, 512, LDS_QKV, stream>>>(
        xb, wqb, bq, Qb, Bn * S, D, D, 1.0f, 0, 0, 0);
    gemm_c8<128, true, true><<<gQKV, 512, LDS_QKV, stream>>>(
        yb, wkb, bk, Kb, Bn * S, D, D, 1.0f, 0, 0, 0);
    gemm_c8<128, true, true><<<gQKV, 512, LDS_QKV, stream>>>(
        zb, wvb, bv, Vb, Bn * S, D, D, 1.0f, 0, 0, 0);

    transpose_bf16<<<dim3(D / 64, S / 64, Bn), 256, 0, stream>>>(Vb, Vt);

    // scores: P = (Q K^T) / 32   (8 x 8 x 4 = 256 blocks, BN=256)
    gemm_c8<256, true, false><<<dim3(S / 256, S / 256, Bn), 512, LDS_SC, stream>>>(
        Qb, Kb, nullptr, Pb, S, S, D, 0.03125f,
        (long long)S * D, (long long)S * D, (long long)S * S);

    softmax_kernel<<<Bn * S, 256, 0, stream>>>(Pb);

    // out = P @ V (via Vt), fp32   (8 x 8 x 4 = 256 blocks, BN=128)
    gemm_c8<128, false, false><<<dim3(D / 128, S / 256, Bn), 512, LDS_QKV, stream>>>(
        Pb, Vt, nullptr, d_out, S, D, S, 1.0f,
        (long long)S * S, (long long)D * S, (long long)S * D);
}

// Round 8
// 300.963 us; speedup vs baseline: 1.1031x; 1.0739x over previous
//
#include <hip/hip_runtime.h>
#include <hip/hip_bf16.h>

typedef unsigned short u16;
typedef __bf16 bf16x8 __attribute__((ext_vector_type(8)));
typedef float  f32x4  __attribute__((ext_vector_type(4)));
typedef u16    u16x8  __attribute__((ext_vector_type(8)));

__device__ __forceinline__ u16 f2bf(float f) {
    unsigned u = __float_as_uint(f);
    u = (u + 0x7fffu + ((u >> 16) & 1u)) >> 16;   // RNE
    return (u16)u;
}

// ---------------------------------------------------------------- zero (row-sum buffer)
__global__ __launch_bounds__(256) void zero_kernel(float* __restrict__ p, int n)
{
    int i = blockIdx.x * 256 + threadIdx.x;
    if (i < n) p[i] = 0.0f;
}

// ---------------------------------------------------------------- convert (3 tensors per dispatch)
__global__ __launch_bounds__(256) void cvt3_bf16_kernel(
    const float* __restrict__ s0, const float* __restrict__ s1,
    const float* __restrict__ s2, u16* __restrict__ dst, size_t dstride, int n8)
{
    int i = blockIdx.x * 256 + threadIdx.x;
    if (i >= n8) return;
    const float* src = (blockIdx.z == 0) ? s0 : (blockIdx.z == 1) ? s1 : s2;
    u16* d = dst + (size_t)blockIdx.z * dstride;
    const float4* s4 = (const float4*)src;
    float4 a = s4[2 * i], b = s4[2 * i + 1];
    u16x8 o;
    o[0] = f2bf(a.x); o[1] = f2bf(a.y); o[2] = f2bf(a.z); o[3] = f2bf(a.w);
    o[4] = f2bf(b.x); o[5] = f2bf(b.y); o[6] = f2bf(b.z); o[7] = f2bf(b.w);
    ((u16x8*)d)[i] = o;
}

// ---------------------------------------------------------------- GEMM C = A*B^T  (R4 core, proven)
// BM=256, BN=128, BK=64, 8 waves (4M x 2N), wave tile 64x64, reads pipelined
// one phase ahead, 3 LDS buffers (144KB) distance-2, counted vmcnt(6),
// ONE barrier per tile, T1 XCD remap + L2 shaping, T2 XOR-swizzle, T5 setprio.
// MODE: 0 = bias + bf16 out (QKV, z selects bias)
//       1 = exp(scale*acc) + bf16 out + row-sum atomicAdd (scores)
//       2 = acc / rowsum, f32 out (PV)
#define BUF_N 24576   // u16 per buffer: A 256*64=16384 + B 128*64=8192
#define LDS_N (3 * BUF_N * 2)  // 147456 bytes

__device__ __forceinline__ void gload_lds16(const void* g, void* l) {
    __builtin_amdgcn_global_load_lds(
        (__attribute__((address_space(1))) void*)g,
        (__attribute__((address_space(3))) void*)l, 16, 0, 0);
}

template<int MODE>
__global__ __launch_bounds__(512, 2) void gemm_p(
    const u16* __restrict__ A, const u16* __restrict__ Bm,
    const float* __restrict__ bz0, const float* __restrict__ bz1,
    const float* __restrict__ bz2, void* __restrict__ C,
    float* __restrict__ rowsum,
    int M, int N, int K, float scale,
    long long aBS, long long bBS, long long cBS)
{
    extern __shared__ u16 lds[];

    // ---- T1: XCD-aware remap + L2 group shaping (4 m-rows per group) ----
    const int gx = gridDim.x, gy = gridDim.y;
    const int slab = gx * gy;
    const int nwg  = slab * gridDim.z;
    const int b    = blockIdx.x + gx * (blockIdx.y + gy * blockIdx.z);
    const int qc   = nwg >> 3;
    const int L    = (b & 7) * qc + (b >> 3);
    const int tz   = L / slab;
    const int rr   = L - tz * slab;
    const int g4   = rr / (gx * 4);
    const int w4   = rr - g4 * (gx * 4);
    const int tx   = w4 >> 2;
    const int ty   = g4 * 4 + (w4 & 3);

    A  += (size_t)tz * aBS;
    Bm += (size_t)tz * bBS;

    const int m0 = ty * 256;
    const int n0 = tx * 128;
    const int tid  = threadIdx.x;
    const int lane = tid & 63;
    const int wave = tid >> 6;          // 0..7
    const int wm   = wave >> 1;         // 0..3  (64-row slice of A)
    const int wn   = wave & 1;          // 0..1  (64-row slice of B)
    const int fr   = lane & 15;
    const int kg   = lane >> 4;         // 0..3

    // ---- staging: linear LDS dest, inverse-swizzled global source (rule #21)
    const int rl  = tid >> 3;                    // 0..63 row within chunk
    const int sw8 = ((tid & 7) ^ (rl & 7)) * 8;  // swizzled 16B slot (u16 units)
    const u16* gA = A  + (size_t)(m0 + rl) * K + sw8;
    const u16* gB = Bm + (size_t)(n0 + rl) * K + sw8;
    const int ldsW = wave * 512;                 // u16

    auto stA = [&](u16* bufb, int tk, int c) {   // c = 0..3
        gload_lds16(gA + (size_t)c * 64 * K + (size_t)tk * 64,
                    bufb + c * 4096 + ldsW);
    };
    auto stB = [&](u16* bufb, int tk, int c) {   // c = 0..1
        gload_lds16(gB + (size_t)c * 64 * K + (size_t)tk * 64,
                    bufb + 16384 + c * 4096 + ldsW);
    };

    // ---- fragment reads (swizzled slot)
    auto rdA = [&](const u16* sa, int m, int ks) {
        return *(const bf16x8*)&sa[(wm * 64 + m * 16 + fr) * 64
                                   + ((((ks << 2) | kg) ^ (fr & 7)) << 3)];
    };
    auto rdB = [&](const u16* sb, int n, int ks) {
        return *(const bf16x8*)&sb[(wn * 64 + n * 16 + fr) * 64
                                   + ((((ks << 2) | kg) ^ (fr & 7)) << 3)];
    };

    f32x4 acc[4][4] = {};
    bf16x8 a0[4], b0[4], a1[4], b1[4];
    const int NT = K / 64;

    u16 *p0 = lds, *p1 = lds + BUF_N, *p2 = lds + 2 * BUF_N;

    // ---- prologue: stage t0->p0, t1->p1; wait t0 (6 newest stay in flight)
    #pragma unroll
    for (int c = 0; c < 4; ++c) stA(p0, 0, c);
    #pragma unroll
    for (int c = 0; c < 2; ++c) stB(p0, 0, c);
    #pragma unroll
    for (int c = 0; c < 4; ++c) stA(p1, 1, c);
    #pragma unroll
    for (int c = 0; c < 2; ++c) stB(p1, 1, c);
    asm volatile("s_waitcnt vmcnt(6)" ::: "memory");
    __builtin_amdgcn_s_barrier();

    // preload phase-0 fragments of tile 0
    #pragma unroll
    for (int m = 0; m < 4; ++m) a0[m] = rdA(p0, m, 0);
    #pragma unroll
    for (int n = 0; n < 4; ++n) b0[n] = rdB(p0 + 16384, n, 0);

    for (int t = 0; t < NT; ++t) {
        const u16* sa = p0;
        const u16* sb = p0 + 16384;
        const bool st = (t + 2 < NT);

        // ========== phase 0: issue ks1 reads + all staging, MFMA ks0 ==========
        #pragma unroll
        for (int m = 0; m < 4; ++m) a1[m] = rdA(sa, m, 1);
        #pragma unroll
        for (int n = 0; n < 4; ++n) b1[n] = rdB(sb, n, 1);
        if (st) {
            #pragma unroll
            for (int c = 0; c < 4; ++c) stA(p2, t + 2, c);
            #pragma unroll
            for (int c = 0; c < 2; ++c) stB(p2, t + 2, c);
        }
        __builtin_amdgcn_s_setprio(1);
        #pragma unroll
        for (int m = 0; m < 4; ++m)
            #pragma unroll
            for (int n = 0; n < 4; ++n)
                acc[m][n] = __builtin_amdgcn_mfma_f32_16x16x32_bf16(
                    a0[m], b0[n], acc[m][n], 0, 0, 0);
        __builtin_amdgcn_s_setprio(0);

        // ========== phase 1: drain, counted vmcnt, barrier, next-tile reads ==========
        asm volatile("s_waitcnt lgkmcnt(0)" ::: "memory");
        if (st) asm volatile("s_waitcnt vmcnt(6)" ::: "memory");
        else    asm volatile("s_waitcnt vmcnt(0)" ::: "memory");
        __builtin_amdgcn_s_barrier();
        if (t + 1 < NT) {
            const u16* na = p1;
            const u16* nb = p1 + 16384;
            #pragma unroll
            for (int m = 0; m < 4; ++m) a0[m] = rdA(na, m, 0);
            #pragma unroll
            for (int n = 0; n < 4; ++n) b0[n] = rdB(nb, n, 0);
        }
        __builtin_amdgcn_s_setprio(1);
        #pragma unroll
        for (int m = 0; m < 4; ++m)
            #pragma unroll
            for (int n = 0; n < 4; ++n)
                acc[m][n] = __builtin_amdgcn_mfma_f32_16x16x32_bf16(
                    a1[m], b1[n], acc[m][n], 0, 0, 0);
        __builtin_amdgcn_s_setprio(0);

        u16* tmp = p0; p0 = p1; p1 = p2; p2 = tmp;
    }

    // ---- epilogue: row = m0+wm*64+m*16+kg*4+q, col = n0+wn*64+n*16+fr
    if constexpr (MODE == 0) {
        const float* bias = (tz == 0) ? bz0 : (tz == 1) ? bz1 : bz2;
        u16* Cb = (u16*)C + (size_t)tz * cBS;
        #pragma unroll
        for (int m = 0; m < 4; ++m) {
            const int row0 = m0 + wm * 64 + m * 16 + kg * 4;
            #pragma unroll
            for (int n = 0; n < 4; ++n) {
                const int col = n0 + wn * 64 + n * 16 + fr;
                const float badd = bias[col];
                f32x4 v = acc[m][n];
                #pragma unroll
                for (int q = 0; q < 4; ++q)
                    Cb[(size_t)(row0 + q) * N + col] = f2bf(v[q] * scale + badd);
            }
        }
    } else if constexpr (MODE == 1) {
        // exp + store bf16 + wave-local row partial sums + atomicAdd
        u16* Cb = (u16*)C + (size_t)tz * cBS;
        float rs[4][4];   // [m][q]
        #pragma unroll
        for (int m = 0; m < 4; ++m)
            #pragma unroll
            for (int q = 0; q < 4; ++q) rs[m][q] = 0.0f;
        #pragma unroll
        for (int m = 0; m < 4; ++m) {
            const int row0 = m0 + wm * 64 + m * 16 + kg * 4;
            #pragma unroll
            for (int n = 0; n < 4; ++n) {
                const int col = n0 + wn * 64 + n * 16 + fr;
                f32x4 v = acc[m][n];
                #pragma unroll
                for (int q = 0; q < 4; ++q) {
                    float e = __expf(v[q] * scale);
                    rs[m][q] += e;
                    Cb[(size_t)(row0 + q) * N + col] = f2bf(e);
                }
            }
        }
        // reduce over the 16-lane fr-group (bits 0..3 of lane)
        #pragma unroll
        for (int m = 0; m < 4; ++m)
            #pragma unroll
            for (int q = 0; q < 4; ++q) {
                float v = rs[m][q];
                v += __shfl_xor(v, 1, 64);
                v += __shfl_xor(v, 2, 64);
                v += __shfl_xor(v, 4, 64);
                v += __shfl_xor(v, 8, 64);
                rs[m][q] = v;
            }
        if (fr == 0) {
            float* rsb = rowsum + (size_t)tz * M;
            #pragma unroll
            for (int m = 0; m < 4; ++m) {
                const int row0 = m0 + wm * 64 + m * 16 + kg * 4;
                #pragma unroll
                for (int q = 0; q < 4; ++q)
                    atomicAdd(&rsb[row0 + q], rs[m][q]);
            }
        }
    } else {
        // divide by row-sum, f32 out
        float* Cf = (float*)C + (size_t)tz * cBS;
        const float* rsb = rowsum + (size_t)tz * M;
        #pragma unroll
        for (int m = 0; m < 4; ++m) {
            const int row0 = m0 + wm * 64 + m * 16 + kg * 4;
            const f32x4 s4 = *(const f32x4*)&rsb[row0];
            #pragma unroll
            for (int n = 0; n < 4; ++n) {
                const int col = n0 + wn * 64 + n * 16 + fr;
                f32x4 v = acc[m][n];
                #pragma unroll
                for (int q = 0; q < 4; ++q)
                    Cf[(size_t)(row0 + q) * N + col] = v[q] / s4[q];
            }
        }
    }
}

// ---------------------------------------------------------------- V transpose
__global__ __launch_bounds__(256) void transpose_bf16(
    const u16* __restrict__ V, u16* __restrict__ Vt)
{
    __shared__ u16 tile[64][72];
    const int b  = blockIdx.z;
    const int k0 = blockIdx.y * 64;
    const int d0 = blockIdx.x * 64;
    const int tr = threadIdx.x >> 3;
    const int tc = (threadIdx.x & 7) * 8;

    const u16* src = V + ((size_t)b * 2048 + k0) * 1024 + d0;
    #pragma unroll
    for (int i = 0; i < 2; ++i) {
        int r = tr + i * 32;
        *(u16x8*)&tile[r][tc] = *(const u16x8*)&src[(size_t)r * 1024 + tc];
    }
    __syncthreads();
    u16* dst = Vt + ((size_t)b * 1024 + d0) * 2048 + k0;
    #pragma unroll
    for (int i = 0; i < 2; ++i) {
        int r = tr + i * 32;
        u16x8 o;
        #pragma unroll
        for (int j = 0; j < 8; ++j) o[j] = tile[tc + j][r];
        *(u16x8*)&dst[(size_t)r * 2048 + tc] = o;
    }
}

// ---------------------------------------------------------------- launch
extern "C" void kernel_launch(void* const* d_in, const int* in_sizes, int n_in,
                              void* d_out, int out_size, void* d_ws, size_t ws_size,
                              hipStream_t stream)
{
    const int Bn = 4, S = 2048, D = 1024;
    const size_t nx = (size_t)Bn * S * D;
    const size_t nw = (size_t)D * D;

    const float* x  = (const float*)d_in[0];
    const float* y  = (const float*)d_in[1];
    const float* z  = (const float*)d_in[2];
    const float* Wq = (const float*)d_in[3];
    const float* bq = (const float*)d_in[4];
    const float* Wk = (const float*)d_in[5];
    const float* bk = (const float*)d_in[6];
    const float* Wv = (const float*)d_in[7];
    const float* bv = (const float*)d_in[8];

    u16* xb  = (u16*)d_ws;          // [3][nx]: x,y,z bf16 (contiguous for merged QKV)
    u16* wqb = xb + 3 * nx;         // [3][nw]: Wq,Wk,Wv
    u16* Qb  = wqb + 3 * nw;        // [3][nx]: Q,K,V (contiguous outputs)
    u16* Kb  = Qb + nx;
    u16* Vb  = Kb + nx;
    u16* Vt  = Vb + nx;             // [B][D][S]
    float* sums = (float*)(Vt + nx);   // [B][S] row-sums of exp(scores)
    u16* Pb  = xb;                  // P [B][S][S] aliases x/y bf16 (dead after QKV)

    hipFuncSetAttribute((const void*)gemm_p<0>,
                        hipFuncAttributeMaxDynamicSharedMemorySize, LDS_N);
    hipFuncSetAttribute((const void*)gemm_p<1>,
                        hipFuncAttributeMaxDynamicSharedMemorySize, LDS_N);
    hipFuncSetAttribute((const void*)gemm_p<2>,
                        hipFuncAttributeMaxDynamicSharedMemorySize, LDS_N);

    zero_kernel<<<(Bn * S + 255) / 256, 256, 0, stream>>>(sums, Bn * S);

    const int n8x = (int)(nx / 8), n8w = (int)(nw / 8);
    cvt3_bf16_kernel<<<dim3((n8x + 255) / 256, 1, 3), 256, 0, stream>>>(
        x, y, z, xb, nx, n8x);
    cvt3_bf16_kernel<<<dim3((n8w + 255) / 256, 1, 3), 256, 0, stream>>>(
        Wq, Wk, Wv, wqb, nw, n8w);

    // merged QKV: z in {0,1,2} -> (x,Wq,bq,Q), (y,Wk,bk,K), (z,Wv,bv,V)
    gemm_p<0><<<dim3(D / 128, (Bn * S) / 256, 3), 512, LDS_N, stream>>>(
        xb, wqb, bq, bk, bv, Qb, nullptr, Bn * S, D, D, 1.0f,
        (long long)nx, (long long)nw, (long long)nx);

    transpose_bf16<<<dim3(D / 64, S / 64, Bn), 256, 0, stream>>>(Vb, Vt);

    // scores: P' = exp((Q K^T) / 32), bf16 + row-sum atomics  (512 blocks)
    gemm_p<1><<<dim3(S / 128, S / 256, Bn), 512, LDS_N, stream>>>(
        Qb, Kb, nullptr, nullptr, nullptr, Pb, sums, S, S, D, 0.03125f,
        (long long)S * D, (long long)S * D, (long long)S * S);

    // out = (P' @ V) / rowsum, f32  (256 blocks)
    gemm_p<2><<<dim3(D / 128, S / 256, Bn), 512, LDS_N, stream>>>(
        Pb, Vt, nullptr, nullptr, nullptr, d_out, sums, S, D, S, 1.0f,
        (long long)S * S, (long long)D * S, (long long)S * D);
}